// Round 4
// baseline (29.167 us; speedup 1.0000x reference)
//
#include <hip/hip_runtime.h>

// out[b,e,t] = sum_{s<=t} x[s]*(w0[s]*dv0^(t-s) + w1[t]*dv1^(t-s)) + bias[t]
//   P[t] = dv0*P[t-1] + x[t]*w0[t];  Q[t] = dv1*Q[t-1] + x[t]
//   out[t] = P[t] + w1[t]*Q[t] + bias[t]
// 4 rows per 256-thread block (2048 blocks): shared w0/w1/bias loaded once
// per block, x for all 4 rows loaded up front (MLP), 4 independent scans
// (ILP), one barrier for the cross-wave carry exchange, fused epilogue with
// nontemporal float4 stores.

#define S_LEN 2048
#define THREADS 256
#define RPB 4                       // rows per block

typedef float f4 __attribute__((ext_vector_type(4)));

__global__ __launch_bounds__(THREADS, 4)
void crcl_kernel(const float* __restrict__ x,
                 const float* __restrict__ weight,
                 const float* __restrict__ bias,
                 const float* __restrict__ decay,
                 float* __restrict__ out,
                 int nrows)
{
    __shared__ float carry[2][RPB][4];   // [p/q][row][wave]

    const int t    = (int)threadIdx.x;
    const int lane = t & 63;
    const int w    = t >> 6;
    const long row0 = (long)blockIdx.x * RPB;

    // ---- shared arrays: once per block ----
    const f4* w04 = (const f4*)weight;            // weight[0][:]
    const f4* w14 = (const f4*)(weight + S_LEN);  // weight[1][:]
    const f4* b4  = (const f4*)bias;
    const f4 wa = w04[2 * t], wb = w04[2 * t + 1];
    const f4 va = w14[2 * t], vb = w14[2 * t + 1];
    const f4 ba = b4[2 * t],  bb = b4[2 * t + 1];

    // ---- x for all rows up front (memory-level parallelism) ----
    f4 xa[RPB], xb[RPB];
#pragma unroll
    for (int r = 0; r < RPB; ++r) {
        long rr = row0 + r; if (rr >= nrows) rr = nrows - 1;
        const f4* x4 = (const f4*)(x + rr * (long)S_LEN);
        xa[r] = x4[2 * t];
        xb[r] = x4[2 * t + 1];
    }

    const float dv0 = fminf(fmaxf(decay[0], 0.9f), 1.0f);
    const float dv1 = fminf(fmaxf(decay[1], 0.9f), 1.0f);

    // ---- pass 1: per-thread segment totals, 4 independent chains ----
    float pc[RPB], qc[RPB];
#pragma unroll
    for (int r = 0; r < RPB; ++r) {
        float pcr = 0.0f, qcr = 0.0f;
#pragma unroll
        for (int j = 0; j < 4; ++j) {
            pcr = fmaf(dv0, pcr, xa[r][j] * wa[j]);
            qcr = fmaf(dv1, qcr, xa[r][j]);
        }
#pragma unroll
        for (int j = 0; j < 4; ++j) {
            pcr = fmaf(dv0, pcr, xb[r][j] * wb[j]);
            qcr = fmaf(dv1, qcr, xb[r][j]);
        }
        pc[r] = pcr; qc[r] = qcr;
    }

    // ---- wave Kogge-Stone scan of segment carries, all rows together ----
    float A8_0 = dv0 * dv0; A8_0 *= A8_0; A8_0 *= A8_0;   // dv0^8
    float A8_1 = dv1 * dv1; A8_1 *= A8_1; A8_1 *= A8_1;   // dv1^8

    float cp[RPB], cq[RPB];
#pragma unroll
    for (int r = 0; r < RPB; ++r) { cp[r] = pc[r]; cq[r] = qc[r]; }

    float k0 = A8_0, k1 = A8_1;
#pragma unroll
    for (int d = 1; d < 64; d <<= 1) {
#pragma unroll
        for (int r = 0; r < RPB; ++r) {
            const float up = __shfl_up(cp[r], (unsigned)d, 64);
            const float uq = __shfl_up(cq[r], (unsigned)d, 64);
            if (lane >= d) {
                cp[r] = fmaf(k0, up, cp[r]);
                cq[r] = fmaf(k1, uq, cq[r]);
            }
        }
        k0 *= k0;
        k1 *= k1;
    }

    float cin_p[RPB], cin_q[RPB];
#pragma unroll
    for (int r = 0; r < RPB; ++r) {
        cin_p[r] = __shfl_up(cp[r], 1u, 64);
        cin_q[r] = __shfl_up(cq[r], 1u, 64);
        if (lane == 0) { cin_p[r] = 0.0f; cin_q[r] = 0.0f; }
    }

    // ---- cross-wave carry combine (single barrier for all rows) ----
    if (lane == 63) {
#pragma unroll
        for (int r = 0; r < RPB; ++r) {
            carry[0][r][w] = cp[r];
            carry[1][r][w] = cq[r];
        }
    }
    __syncthreads();

    float A512_0 = A8_0, A512_1 = A8_1;                   // dv^512
#pragma unroll
    for (int b = 0; b < 6; ++b) { A512_0 *= A512_0; A512_1 *= A512_1; }

    // lane power dv^(8*lane), row-independent (computed once)
    const float e8 = (float)(8 * lane);
    const float pwl_0 = exp2f(e8 * log2f(dv0));
    const float pwl_1 = exp2f(e8 * log2f(dv1));

#pragma unroll
    for (int r = 0; r < RPB; ++r) {
        float cwp = 0.0f, cwq = 0.0f;
#pragma unroll
        for (int v = 0; v < 3; ++v) {
            if (v < w) {
                cwp = fmaf(cwp, A512_0, carry[0][r][v]);
                cwq = fmaf(cwq, A512_1, carry[1][r][v]);
            }
        }
        cin_p[r] = fmaf(cwp, pwl_0, cin_p[r]);
        cin_q[r] = fmaf(cwq, pwl_1, cin_q[r]);
    }

    // ---- pass 2: recompute seeded with carry, fused epilogue + NT store ----
#pragma unroll
    for (int r = 0; r < RPB; ++r) {
        long rr = row0 + r; if (rr >= nrows) rr = nrows - 1;
        float p2 = cin_p[r], q2 = cin_q[r];
        f4 ya, yb;
#pragma unroll
        for (int j = 0; j < 4; ++j) {
            p2 = fmaf(dv0, p2, xa[r][j] * wa[j]);
            q2 = fmaf(dv1, q2, xa[r][j]);
            ya[j] = fmaf(va[j], q2, p2) + ba[j];
        }
#pragma unroll
        for (int j = 0; j < 4; ++j) {
            p2 = fmaf(dv0, p2, xb[r][j] * wb[j]);
            q2 = fmaf(dv1, q2, xb[r][j]);
            yb[j] = fmaf(vb[j], q2, p2) + bb[j];
        }
        f4* o4 = (f4*)(out + rr * (long)S_LEN);
        __builtin_nontemporal_store(ya, &o4[2 * t]);
        __builtin_nontemporal_store(yb, &o4[2 * t + 1]);
    }
}

extern "C" void kernel_launch(void* const* d_in, const int* in_sizes, int n_in,
                              void* d_out, int out_size, void* d_ws, size_t ws_size,
                              hipStream_t stream) {
    const float* x      = (const float*)d_in[0];
    const float* weight = (const float*)d_in[1];
    const float* bias   = (const float*)d_in[2];
    const float* decay  = (const float*)d_in[3];
    float* out = (float*)d_out;

    const int nrows   = in_sizes[0] / S_LEN;              // B*E = 8192
    const int nblocks = (nrows + RPB - 1) / RPB;          // 2048
    hipLaunchKernelGGL(crcl_kernel, dim3(nblocks), dim3(THREADS), 0, stream,
                       x, weight, bias, decay, out, nrows);
}